// Round 15
// baseline (132.613 us; speedup 1.0000x reference)
//
#include <hip/hip_runtime.h>
#include <hip/hip_bf16.h>
#include <math.h>

// ---------------- problem constants (B=1) ----------------
constexpr int NRIG = 512;
constexpr int NRES = 448;
constexpr int CS   = 384;
constexpr int CZ   = 128;
constexpr int CH   = 16;
constexpr int NH   = 12;
constexpr int PQ   = 4;
constexpr int PV   = 8;
constexpr int HC   = NH * CH;        // 192
constexpr int NPAIR = NRES*NRES;     // 200704
constexpr float INF_ = 100000.0f;
constexpr float SC_ = 0.57735026918962584f;    // sqrt(1/3)

// ---------------- workspace layout (floats) ----------------
constexpr size_t OFF_Q   = 0;                                // [12][512][16]
constexpr size_t OFF_KT  = OFF_Q   + (size_t)NH*NRIG*16;     // [12][16][512]
constexpr size_t OFF_QP  = OFF_KT  + (size_t)NH*16*NRIG;     // [12][512][12]
constexpr size_t OFF_KPT = OFF_QP  + (size_t)NH*NRIG*12;     // [12][12][512]
constexpr size_t OFF_VT  = OFF_KPT + (size_t)NH*12*NRIG;     // [12][40][512]
constexpr size_t OFF_O   = OFF_VT  + (size_t)NH*40*NRIG;     // [512][12][16]
constexpr size_t OFF_OPT = OFF_O   + (size_t)NRIG*HC;        // [512][12][24]
constexpr size_t OFF_RS  = OFF_OPT + (size_t)NRIG*NH*PV*3;   // [512][12]
constexpr size_t OFF_BP  = OFF_RS  + (size_t)NRIG*NH;        // [12][200704]
constexpr size_t OFF_RAW = OFF_BP  + (size_t)NH*NPAIR;       // [512][576]
constexpr size_t OFF_F   = OFF_RAW + (size_t)NRIG*576;       // [512][960]
constexpr size_t OFF_P3  = OFF_F   + (size_t)NRIG*960;       // [3][512][384]

constexpr int ZWB_BLOCKS = NPAIR/64;   // 3136 blocks x 64 rows

// =====================================================================
// Kernel 1: prep = zwb (blocks [0,3136)) | proj_gemm (blocks [3136,3424))
// zwb: bp[h][r] = (z[r,:].w_b[:,h] + b_b[h])*SC.
//   Wave = h-TRIPLE; lane: oct=lane>>3 (row), kl=lane&7 (16-float k-chunk).
//   wv[16][3] preloaded AND PINNED via empty asm (R14 post-mortem: without
//   the pin the compiler rematerializes ~48 wb loads into every pass ->
//   L1-tag-rate bound, VGPR_Count=52; with pin: ~95 VGPR, pure-reg loop).
//   1-deep register double-buffer of z; reduce via 3 shfl_xor.
// proj: C[512][1152] = s @ [wq|wkv|wqp|wkvp] -> Q/KT/VT/RAW.
// =====================================================================
__global__ __launch_bounds__(256, 4) void prep_kernel(
    const float* __restrict__ z,  const float* __restrict__ wb, const float* __restrict__ bb,
    const float* __restrict__ s,
    const float* __restrict__ wq,  const float* __restrict__ bq,
    const float* __restrict__ wkv, const float* __restrict__ bkv,
    const float* __restrict__ wqp, const float* __restrict__ bqp,
    const float* __restrict__ wkvp,const float* __restrict__ bkvp,
    float* __restrict__ ws)
{
    __shared__ float smem[3200];        // proj only: sA[32][68] + sB[32][32]
    const int t = threadIdx.x;

    if ((int)blockIdx.x < ZWB_BLOCKS) {
        // ---------------- zwb: pinned-register w, reg double-buffer ----------------
        const int lane = t & 63;
        const int w    = t >> 6;          // h-triple 0..3 (h = 3w..3w+2)
        const int oct  = lane >> 3;       // row within pass
        const int kl   = lane & 7;        // k-chunk id
        const int kbase = kl << 4;
        const size_t r0 = (size_t)blockIdx.x * 64;

        float wv[16][3];
        #pragma unroll
        for (int kk = 0; kk < 16; ++kk) {
            #pragma unroll
            for (int j = 0; j < 3; ++j)
                wv[kk][j] = wb[(size_t)(kbase + kk)*12 + 3*w + j];
        }
        // PIN: forbid rematerialization — compiler must keep wv in VGPRs.
        #pragma unroll
        for (int kk = 0; kk < 16; ++kk) {
            asm volatile("" : "+v"(wv[kk][0]), "+v"(wv[kk][1]), "+v"(wv[kk][2]));
        }

        const float bb0 = bb[3*w+0], bb1 = bb[3*w+1], bb2 = bb[3*w+2];
        float* bp = ws + OFF_BP + (size_t)(3*w)*NPAIR;

        float4 zbA0, zbA1, zbA2, zbA3;    // buffer A
        float4 zbB0, zbB1, zbB2, zbB3;    // buffer B
        {
            const float4* zp = (const float4*)(z + (r0 + oct)*CZ + kbase);
            zbA0 = zp[0]; zbA1 = zp[1]; zbA2 = zp[2]; zbA3 = zp[3];
        }
        #pragma unroll
        for (int p = 0; p < 8; ++p) {
            // prefetch next pass into the other buffer
            if (p < 7) {
                const float4* zp = (const float4*)(z + (r0 + (size_t)(p+1)*8 + oct)*CZ + kbase);
                if ((p & 1) == 0) { zbB0 = zp[0]; zbB1 = zp[1]; zbB2 = zp[2]; zbB3 = zp[3]; }
                else              { zbA0 = zp[0]; zbA1 = zp[1]; zbA2 = zp[2]; zbA3 = zp[3]; }
            }
            const float4 c0 = ((p & 1) == 0) ? zbA0 : zbB0;
            const float4 c1 = ((p & 1) == 0) ? zbA1 : zbB1;
            const float4 c2 = ((p & 1) == 0) ? zbA2 : zbB2;
            const float4 c3 = ((p & 1) == 0) ? zbA3 : zbB3;
            const float zr[16] = {c0.x,c0.y,c0.z,c0.w, c1.x,c1.y,c1.z,c1.w,
                                  c2.x,c2.y,c2.z,c2.w, c3.x,c3.y,c3.z,c3.w};
            float a0 = 0.f, a1 = 0.f, a2 = 0.f;
            #pragma unroll
            for (int kk = 0; kk < 16; ++kk) {
                const float zv = zr[kk];
                a0 += zv*wv[kk][0]; a1 += zv*wv[kk][1]; a2 += zv*wv[kk][2];
            }
            a0 += __shfl_xor(a0,1); a0 += __shfl_xor(a0,2); a0 += __shfl_xor(a0,4);
            a1 += __shfl_xor(a1,1); a1 += __shfl_xor(a1,2); a1 += __shfl_xor(a1,4);
            a2 += __shfl_xor(a2,1); a2 += __shfl_xor(a2,2); a2 += __shfl_xor(a2,4);
            if (kl == 0) {
                const size_t r = r0 + (size_t)p*8 + oct;
                bp[r]                   = (a0 + bb0) * SC_;
                bp[(size_t)NPAIR + r]   = (a1 + bb1) * SC_;
                bp[(size_t)2*NPAIR + r] = (a2 + bb2) * SC_;
            }
        }
    } else {
        // ---------------- proj_gemm ----------------
        constexpr int BM=64, BN=32, BK=32, LDA=68;
        float (*sA)[LDA] = (float(*)[LDA])smem;          // [32][68]
        float (*sB)[BN]  = (float(*)[BN])(smem + 2176);  // [32][32]
        const int bid = (int)blockIdx.x - ZWB_BLOCKS;
        const int m0 = (bid & 7) * BM;
        const int c0 = (bid >> 3) * BN;
        const int tx = t & 15, ty = t >> 4;

        float acc[4][2] = {};
        for (int kt = 0; kt < CS/BK; ++kt) {
            const int k0 = kt*BK;
            #pragma unroll
            for (int r = 0; r < 2; ++r) {
                int qd = r*256 + t;
                int m = qd >> 3, kq = (qd & 7) << 2;
                float4 f = *(const float4*)(s + (size_t)(m0+m)*CS + k0 + kq);
                sA[kq+0][m] = f.x; sA[kq+1][m] = f.y;
                sA[kq+2][m] = f.z; sA[kq+3][m] = f.w;
            }
            {
                int kk = t >> 3, c4 = (t & 7) << 2;
                int c = c0 + c4;
                const float* wp; int ld, co;
                if (c < 192)      { wp = wq;   ld = 192; co = c;     }
                else if (c < 576) { wp = wkv;  ld = 384; co = c-192; }
                else if (c < 720) { wp = wqp;  ld = 144; co = c-576; }
                else              { wp = wkvp; ld = 432; co = c-720; }
                float4 f = *(const float4*)(wp + (size_t)(k0+kk)*ld + co);
                *(float4*)&sB[kk][c4] = f;
            }
            __syncthreads();
            #pragma unroll
            for (int kk = 0; kk < BK; ++kk) {
                float4 a = *(const float4*)&sA[kk][ty*4];
                float2 b = *(const float2*)&sB[kk][tx*2];
                acc[0][0] += a.x*b.x; acc[0][1] += a.x*b.y;
                acc[1][0] += a.y*b.x; acc[1][1] += a.y*b.y;
                acc[2][0] += a.z*b.x; acc[2][1] += a.z*b.y;
                acc[3][0] += a.w*b.x; acc[3][1] += a.w*b.y;
            }
            __syncthreads();
        }
        float* qw  = ws + OFF_Q;  float* ktw = ws + OFF_KT;  float* vt = ws + OFF_VT;
        float* raw = ws + OFF_RAW;
        #pragma unroll
        for (int i = 0; i < 4; ++i)
            #pragma unroll
            for (int j = 0; j < 2; ++j) {
                int n = m0 + ty*4 + i;
                int c = c0 + tx*2 + j;
                if (c < 192) {
                    int hh = c >> 4, cc = c & 15;
                    qw[((size_t)hh*NRIG + n)*16 + cc] = acc[i][j] + bq[c];
                } else if (c < 576) {
                    int e = c-192; float val = acc[i][j] + bkv[e];
                    int hh = e >> 5, sub = e & 31;
                    if (sub < CH) ktw[((size_t)hh*16 + sub)*NRIG + n] = val;
                    else          vt [((size_t)hh*40 + (sub-CH))*NRIG + n] = val;
                } else {
                    int e = c-576;
                    float bb_ = (c < 720) ? bqp[e] : bkvp[c-720];
                    raw[(size_t)n*576 + e] = acc[i][j] + bb_;
                }
            }
    }
}

// =====================================================================
// Kernel 2: rotate raw local points -> global frame
// =====================================================================
__global__ __launch_bounds__(256) void rotate_kernel(
    const float* __restrict__ rot, const float* __restrict__ trans,
    const float* __restrict__ raw_in, float* __restrict__ qpw,
    float* __restrict__ kptw, float* __restrict__ vtw)
{
    const int gid = blockIdx.x*256 + threadIdx.x;
    const int n = gid / 192, d = gid % 192;
    const float* raw = raw_in + (size_t)n*576;
    float px, py, pzz;
    if (d < 48) { px = raw[d];      py = raw[48+d];       pzz = raw[96+d]; }
    else { int dd = d-48; px = raw[144+dd]; py = raw[288+dd]; pzz = raw[432+dd]; }
    const float* R = rot   + (size_t)n*9;
    const float* T = trans + (size_t)n*3;
    float gx = R[0]*px + R[1]*py + R[2]*pzz + T[0];
    float gy = R[3]*px + R[4]*py + R[5]*pzz + T[1];
    float gz = R[6]*px + R[7]*py + R[8]*pzz + T[2];
    if (d < 48) {                              // q_pts: d = h*4+p
        int hh = d >> 2, pp = d & 3;
        float* dst = qpw + ((size_t)hh*NRIG + n)*12 + pp*3;
        dst[0]=gx; dst[1]=gy; dst[2]=gz;
    } else {
        int dd = d-48; int hh = dd/12, pp = dd%12;
        if (pp < PQ) {
            float* kpt = kptw + (size_t)hh*12*NRIG;
            kpt[(size_t)(pp*3+0)*NRIG + n] = gx;
            kpt[(size_t)(pp*3+1)*NRIG + n] = gy;
            kpt[(size_t)(pp*3+2)*NRIG + n] = gz;
        } else {
            float* vt = vtw + ((size_t)hh*40 + 16 + (pp-PQ)*3)*NRIG + n;
            vt[0*NRIG]=gx; vt[1*NRIG]=gy; vt[2*NRIG]=gz;
        }
    }
}

// =====================================================================
// Kernel 3: attention. block = (h, 8 queries), 256 threads.
// =====================================================================
__global__ __launch_bounds__(256) void attn_kernel(
    const float* __restrict__ hw_in, const float* __restrict__ mask,
    const int* __restrict__ ridx,
    const float* __restrict__ qw_all,  const float* __restrict__ ktw_all,
    const float* __restrict__ qpw_all, const float* __restrict__ kpt_all,
    const float* __restrict__ vt_all,  const float* __restrict__ bp_all,
    float* __restrict__ o_out, float* __restrict__ opt_out, float* __restrict__ rs_out)
{
    constexpr int TI = 8;
    const int h    = blockIdx.x;
    const int i0   = blockIdx.y * TI;
    const int t    = threadIdx.x;
    const int lane = t & 63, wid = t >> 6;

    __shared__ float sE[TI*516];        // [qq][516], b32 conflict-free
    __shared__ float sP[16][TI][45];    // partial sums [g][qq][comp]
    __shared__ float sS[TI];

    const float* qw  = qw_all  + (size_t)h*NRIG*16;
    const float* ktw = ktw_all + (size_t)h*16*NRIG;
    const float* qpw = qpw_all + (size_t)h*NRIG*12;
    const float* kpt = kpt_all + (size_t)h*12*NRIG;
    const float* vt  = vt_all  + (size_t)h*40*NRIG;
    const float* bph = bp_all  + (size_t)h*NPAIR;

    const float hwv = -0.5f * log1pf(__expf(hw_in[h])) * 0.13608276348795434f; // -0.5*softplus*sqrt(1/54)
    const float QKS = 0.14433756729740643f;                                    // sqrt(1/48)

    // ---------- phase 1: logits -> exp -> sE ----------
    #pragma unroll
    for (int jj = 0; jj < 2; ++jj) {
        const int j = t + jj*256;
        float kk[16], kpv[12];
        #pragma unroll
        for (int c = 0; c < 16; ++c) kk[c]  = ktw[c*NRIG + j];   // coalesced
        #pragma unroll
        for (int e = 0; e < 12; ++e) kpv[e] = kpt[e*NRIG + j];   // coalesced
        const float mj = mask[j];
        const int   rj = ridx[j];
        #pragma unroll
        for (int qq = 0; qq < TI; ++qq) {
            const float* qv  = qw  + (size_t)(i0+qq)*16;   // uniform -> s_load
            const float* qpv = qpw + (size_t)(i0+qq)*12;   // uniform -> s_load
            const float  mi  = mask[i0+qq];                // uniform
            const int    ri  = ridx[i0+qq];                // uniform
            float dot = 0.f;
            #pragma unroll
            for (int c = 0; c < 16; ++c) dot += qv[c]*kk[c];
            float sq = 0.f;
            #pragma unroll
            for (int e = 0; e < 12; ++e) { float d = qpv[e]-kpv[e]; sq += d*d; }
            const float bv = bph[(size_t)ri*NRES + rj];    // L1-hot 1.8KB row
            const float lgt = dot*QKS + bv + hwv*sq + INF_*(mi*mj - 1.0f);
            sE[qq*516 + j] = __expf(lgt);
        }
    }
    __syncthreads();

    // ---------- phase 2: output GEMM. wave wid owns comps c = wid + 4*ci ----------
    {
        float acc[11][TI];
        #pragma unroll
        for (int ci=0;ci<11;++ci)
            #pragma unroll
            for (int qq=0;qq<TI;++qq) acc[ci][qq]=0.f;

        #pragma unroll
        for (int m = 0; m < 8; ++m) {
            const int j = lane + (m<<6);
            float ev[TI];
            #pragma unroll
            for (int qq=0;qq<TI;++qq) ev[qq] = sE[qq*516 + j];
            #pragma unroll
            for (int ci = 0; ci < 11; ++ci) {
                if (ci < 10 || wid == 0) {
                    const int c = wid + (ci<<2);                       // 0..40
                    const float vv = (c == 40) ? 1.0f : vt[(size_t)c*NRIG + j];
                    #pragma unroll
                    for (int qq=0;qq<TI;++qq) acc[ci][qq] += ev[qq]*vv;
                }
            }
        }
        #pragma unroll
        for (int ci=0;ci<11;++ci)
            if (ci < 10 || wid == 0)
                #pragma unroll
                for (int qq=0;qq<TI;++qq) {
                    acc[ci][qq] += __shfl_xor(acc[ci][qq], 1);
                    acc[ci][qq] += __shfl_xor(acc[ci][qq], 2);
                }
        if ((lane & 3) == 0) {
            const int g = lane >> 2;
            #pragma unroll
            for (int ci=0;ci<11;++ci)
                if (ci < 10 || wid == 0) {
                    const int c = wid + (ci<<2);
                    #pragma unroll
                    for (int qq=0;qq<TI;++qq) sP[g][qq][c] = acc[ci][qq];
                }
        }
    }
    __syncthreads();

    if (t < TI) {
        float S = 0.f;
        #pragma unroll
        for (int g = 0; g < 16; ++g) S += sP[g][t][40];
        sS[t] = S;
    }
    __syncthreads();

    // ---------- epilogue: 8*41 outputs ----------
    for (int e = t; e < TI*41; e += 256) {
        const int qq = e / 41, c = e % 41;
        const int n = i0 + qq;
        float sum = 0.f;
        #pragma unroll
        for (int g = 0; g < 16; ++g) sum += sP[g][qq][c];
        const float val = sum * (1.0f / sS[qq]);
        if (c < 16)       o_out[((size_t)n*NH + h)*CH + c]        = val;
        else if (c < 40)  opt_out[((size_t)n*NH + h)*24 + (c-16)] = val;
        else              rs_out[(size_t)n*NH + h]                = val;
    }
}

// =====================================================================
// Kernel 4: build feats F[512][960]; pz_diag computed in-block.
// =====================================================================
__global__ __launch_bounds__(256) void feats_kernel(
    const float* __restrict__ rot, const float* __restrict__ trans,
    const float* __restrict__ z, const int* __restrict__ ridx,
    const float* __restrict__ wdz, const float* __restrict__ bdz,
    const float* __restrict__ o_ws, const float* __restrict__ optg,
    const float* __restrict__ rs, float* __restrict__ F)
{
    constexpr int TI = 4;
    __shared__ float sZd[TI][CZ];
    __shared__ float sPz[TI][32];
    const int i0 = blockIdx.x*TI;
    const int t  = threadIdx.x;

    for (int e = t; e < TI*CZ; e += 256) {
        int qq = e >> 7, c = e & 127;
        int ri = ridx[i0+qq];
        sZd[qq][c] = z[((size_t)ri*NRES + ri)*CZ + c];
    }
    for (int e = t; e < TI*HC; e += 256) {
        int qq = e/HC, c = e%HC;
        F[(size_t)(i0+qq)*960 + c] = o_ws[(size_t)(i0+qq)*HC + c];
    }
    for (int e = t; e < TI*96; e += 256) {
        int qq = e/96, hp = e%96; int n = i0+qq;
        const float* g = optg + ((size_t)n*NH + hp/PV)*24 + (hp%PV)*3;
        float gx = g[0]-trans[n*3+0], gy = g[1]-trans[n*3+1], gz = g[2]-trans[n*3+2];
        const float* R = rot + (size_t)n*9;
        float lx = R[0]*gx + R[3]*gy + R[6]*gz;   // rot^T
        float ly = R[1]*gx + R[4]*gy + R[7]*gz;
        float lz = R[2]*gx + R[5]*gy + R[8]*gz;
        float* Fr = F + (size_t)n*960;
        Fr[192+hp] = lx; Fr[288+hp] = ly; Fr[384+hp] = lz;
        Fr[480+hp] = sqrtf(lx*lx+ly*ly+lz*lz + 1e-8f);
    }
    __syncthreads();
    if (t < TI*32) {
        int qq = t >> 5, d = t & 31;
        float acc = 0.f;
        #pragma unroll 8
        for (int c = 0; c < CZ; ++c) acc += sZd[qq][c] * wdz[(size_t)c*32 + d];
        sPz[qq][d] = acc + bdz[d];
    }
    __syncthreads();
    for (int e = t; e < TI*384; e += 256) {
        int qq = e/384, hd = e%384; int n = i0+qq;
        F[(size_t)n*960 + 576 + hd] = rs[(size_t)n*NH + (hd>>5)] * sPz[qq][hd&31];
    }
}

// =====================================================================
// Kernel 5: split-K GEMM  P[ks][512][384] = F[:, ks*320..+320] @ w_out-slice
// =====================================================================
__global__ __launch_bounds__(256) void out_gemm_kernel(
    const float* __restrict__ w_out, const float* __restrict__ F,
    float* __restrict__ P)
{
    constexpr int BM=64, BN=32, BK=32, LDA=68;
    __shared__ float sA[BK][LDA];
    __shared__ float sB[BK][BN];
    const int m0 = blockIdx.x * BM;
    const int c0 = blockIdx.y * BN;
    const int ks = blockIdx.z;
    const int t  = threadIdx.x;
    const int tx = t & 15, ty = t >> 4;

    float acc[4][2] = {};
    for (int kt = 0; kt < 10; ++kt) {
        const int k0 = ks*320 + kt*BK;
        #pragma unroll
        for (int r = 0; r < 2; ++r) {
            int qd = r*256 + t;
            int m = qd >> 3, kq = (qd & 7) << 2;
            float4 f = *(const float4*)(F + (size_t)(m0+m)*960 + k0 + kq);
            sA[kq+0][m] = f.x; sA[kq+1][m] = f.y;
            sA[kq+2][m] = f.z; sA[kq+3][m] = f.w;
        }
        {
            int kk = t >> 3, c4 = (t & 7) << 2;
            float4 f = *(const float4*)(w_out + (size_t)(k0+kk)*CS + c0 + c4);
            *(float4*)&sB[kk][c4] = f;
        }
        __syncthreads();
        #pragma unroll
        for (int kk = 0; kk < BK; ++kk) {
            float4 a = *(const float4*)&sA[kk][ty*4];
            float2 b = *(const float2*)&sB[kk][tx*2];
            acc[0][0] += a.x*b.x; acc[0][1] += a.x*b.y;
            acc[1][0] += a.y*b.x; acc[1][1] += a.y*b.y;
            acc[2][0] += a.z*b.x; acc[2][1] += a.z*b.y;
            acc[3][0] += a.w*b.x; acc[3][1] += a.w*b.y;
        }
        __syncthreads();
    }
    #pragma unroll
    for (int i = 0; i < 4; ++i)
        #pragma unroll
        for (int j = 0; j < 2; ++j) {
            int n = m0 + ty*4 + i;
            int c = c0 + tx*2 + j;
            P[(size_t)ks*NRIG*CS + (size_t)n*CS + c] = acc[i][j];
        }
}

// =====================================================================
// Kernel 6: reduce split-K partials + bias
// =====================================================================
__global__ __launch_bounds__(256) void reduce_kernel(
    const float* __restrict__ P, const float* __restrict__ b_out,
    float* __restrict__ out)
{
    const int i4 = blockIdx.x*256 + threadIdx.x;
    const size_t base = (size_t)i4 * 4;
    float4 a = *(const float4*)(P + base);
    float4 b = *(const float4*)(P + (size_t)NRIG*CS + base);
    float4 c = *(const float4*)(P + (size_t)2*NRIG*CS + base);
    const int cc = (int)(base % CS);
    float4 bv = *(const float4*)(b_out + cc);
    float4 r;
    r.x = a.x+b.x+c.x+bv.x; r.y = a.y+b.y+c.y+bv.y;
    r.z = a.z+b.z+c.z+bv.z; r.w = a.w+b.w+c.w+bv.w;
    *(float4*)(out + base) = r;
}

// =====================================================================
extern "C" void kernel_launch(void* const* d_in, const int* in_sizes, int n_in,
                              void* d_out, int out_size, void* d_ws, size_t ws_size,
                              hipStream_t stream)
{
    const float* s     = (const float*)d_in[0];
    const float* z     = (const float*)d_in[1];
    const float* rot   = (const float*)d_in[2];
    const float* trans = (const float*)d_in[3];
    const float* mask  = (const float*)d_in[4];
    const int*   ridx  = (const int*)  d_in[5];
    const float* wq    = (const float*)d_in[6];
    const float* bq    = (const float*)d_in[7];
    const float* wkv   = (const float*)d_in[8];
    const float* bkv   = (const float*)d_in[9];
    const float* wqp   = (const float*)d_in[10];
    const float* bqp   = (const float*)d_in[11];
    const float* wkvp  = (const float*)d_in[12];
    const float* bkvp  = (const float*)d_in[13];
    const float* wb    = (const float*)d_in[14];
    const float* bb    = (const float*)d_in[15];
    const float* wdz   = (const float*)d_in[16];
    const float* bdz   = (const float*)d_in[17];
    const float* hw    = (const float*)d_in[18];
    const float* wout  = (const float*)d_in[19];
    const float* bout  = (const float*)d_in[20];
    float* ws  = (float*)d_ws;
    float* out = (float*)d_out;

    hipLaunchKernelGGL(prep_kernel, dim3(ZWB_BLOCKS + 288), dim3(256), 0, stream,
        z, wb, bb, s, wq,bq, wkv,bkv, wqp,bqp, wkvp,bkvp, ws);
    hipLaunchKernelGGL(rotate_kernel, dim3(NRIG*192/256), dim3(256), 0, stream,
        rot, trans, ws+OFF_RAW, ws+OFF_QP, ws+OFF_KPT, ws+OFF_VT);
    hipLaunchKernelGGL(attn_kernel, dim3(NH, NRIG/8), dim3(256), 0, stream,
        hw, mask, ridx, ws+OFF_Q, ws+OFF_KT, ws+OFF_QP, ws+OFF_KPT,
        ws+OFF_VT, ws+OFF_BP, ws+OFF_O, ws+OFF_OPT, ws+OFF_RS);
    hipLaunchKernelGGL(feats_kernel, dim3(NRIG/4), dim3(256), 0, stream,
        rot, trans, z, ridx, wdz, bdz, ws+OFF_O, ws+OFF_OPT, ws+OFF_RS, ws+OFF_F);
    hipLaunchKernelGGL(out_gemm_kernel, dim3(NRIG/64, CS/32, 3), dim3(256), 0, stream,
        wout, ws+OFF_F, ws+OFF_P3);
    hipLaunchKernelGGL(reduce_kernel, dim3(NRIG*CS/4/256), dim3(256), 0, stream,
        ws+OFF_P3, bout, out);
}

// Round 16
// 106.274 us; speedup vs baseline: 1.2478x; 1.2478x over previous
//
#include <hip/hip_runtime.h>
#include <hip/hip_bf16.h>
#include <math.h>

// ---------------- problem constants (B=1) ----------------
constexpr int NRIG = 512;
constexpr int NRES = 448;
constexpr int CS   = 384;
constexpr int CZ   = 128;
constexpr int CH   = 16;
constexpr int NH   = 12;
constexpr int PQ   = 4;
constexpr int PV   = 8;
constexpr int HC   = NH * CH;        // 192
constexpr int NPAIR = NRES*NRES;     // 200704
constexpr float INF_ = 100000.0f;
constexpr float SC_ = 0.57735026918962584f;    // sqrt(1/3)

// ---------------- workspace layout (floats) ----------------
constexpr size_t OFF_Q   = 0;                                // [12][512][16]
constexpr size_t OFF_KT  = OFF_Q   + (size_t)NH*NRIG*16;     // [12][16][512]
constexpr size_t OFF_QP  = OFF_KT  + (size_t)NH*16*NRIG;     // [12][512][12]
constexpr size_t OFF_KPT = OFF_QP  + (size_t)NH*NRIG*12;     // [12][12][512]
constexpr size_t OFF_VT  = OFF_KPT + (size_t)NH*12*NRIG;     // [12][40][512]
constexpr size_t OFF_O   = OFF_VT  + (size_t)NH*40*NRIG;     // [512][12][16]
constexpr size_t OFF_OPT = OFF_O   + (size_t)NRIG*HC;        // [512][12][24]
constexpr size_t OFF_RS  = OFF_OPT + (size_t)NRIG*NH*PV*3;   // [512][12]
constexpr size_t OFF_BP  = OFF_RS  + (size_t)NRIG*NH;        // [12][200704]
constexpr size_t OFF_RAW = OFF_BP  + (size_t)NH*NPAIR;       // [512][576]
constexpr size_t OFF_F   = OFF_RAW + (size_t)NRIG*576;       // [512][960]
constexpr size_t OFF_P3  = OFF_F   + (size_t)NRIG*960;       // [3][512][384]

constexpr int ZWB_BLOCKS = NPAIR/256;   // 784 blocks x 256 rows

// =====================================================================
// Kernel 1: prep = zwb (blocks [0,784)) | proj_gemm (blocks [784,1072))
// zwb: bp[h][r] = (z[r,:].w_b[:,h] + b_b[h])*SC.
//   Wave = h-TRIPLE; lane: oct=lane>>3 (8 rows/pass), kl=lane&7 (16-float
//   c-chunk). w preload = 48 scalars w0/w1/w2[16], hoisted once per wave.
//   R13-R15 post-mortem: __launch_bounds__(256,4)'s 128-VGPR cap forced the
//   compiler to remat/spill the preload (~48 scattered loads x every pass ->
//   L1-tag bound, 77-100us). Fix: (256,2) -> 256-VGPR cap (need ~85), no
//   dbuf/pin, 256-row blocks (32 passes) so the preload amortizes; 12+
//   waves/CU supply latency hiding.
// proj: C[512][1152] = s @ [wq|wkv|wqp|wkvp] -> Q/KT/VT/RAW.
// =====================================================================
__global__ __launch_bounds__(256, 2) void prep_kernel(
    const float* __restrict__ z,  const float* __restrict__ wb, const float* __restrict__ bb,
    const float* __restrict__ s,
    const float* __restrict__ wq,  const float* __restrict__ bq,
    const float* __restrict__ wkv, const float* __restrict__ bkv,
    const float* __restrict__ wqp, const float* __restrict__ bqp,
    const float* __restrict__ wkvp,const float* __restrict__ bkvp,
    float* __restrict__ ws)
{
    __shared__ float smem[3200];        // proj only: sA[32][68] + sB[32][32]
    const int t = threadIdx.x;

    if ((int)blockIdx.x < ZWB_BLOCKS) {
        // ---------------- zwb ----------------
        const int lane = t & 63;
        const int w    = t >> 6;          // h-triple 0..3 (h = 3w..3w+2)
        const int oct  = lane >> 3;       // row within pass
        const int kl   = lane & 7;        // c-chunk id
        const int kbase = kl << 4;
        const size_t r0 = (size_t)blockIdx.x * 256;

        // hoisted once per wave: 48 scalars (statically indexed everywhere)
        float w0[16], w1[16], w2[16];
        #pragma unroll
        for (int kk = 0; kk < 16; ++kk) {
            const float* wp = wb + (size_t)(kbase + kk)*12 + 3*w;
            w0[kk] = wp[0]; w1[kk] = wp[1]; w2[kk] = wp[2];
        }
        const float bb0 = bb[3*w+0], bb1 = bb[3*w+1], bb2 = bb[3*w+2];
        float* bp = ws + OFF_BP + (size_t)(3*w)*NPAIR;

        for (int p = 0; p < 32; ++p) {
            const size_t row = r0 + (size_t)p*8 + oct;
            const float4* zp = (const float4*)(z + row*CZ + kbase);
            const float4 c0 = zp[0], c1 = zp[1], c2 = zp[2], c3 = zp[3];
            const float zr[16] = {c0.x,c0.y,c0.z,c0.w, c1.x,c1.y,c1.z,c1.w,
                                  c2.x,c2.y,c2.z,c2.w, c3.x,c3.y,c3.z,c3.w};
            float a0 = 0.f, a1 = 0.f, a2 = 0.f;
            #pragma unroll
            for (int kk = 0; kk < 16; ++kk) {
                const float zv = zr[kk];
                a0 += zv*w0[kk]; a1 += zv*w1[kk]; a2 += zv*w2[kk];
            }
            a0 += __shfl_xor(a0,1); a0 += __shfl_xor(a0,2); a0 += __shfl_xor(a0,4);
            a1 += __shfl_xor(a1,1); a1 += __shfl_xor(a1,2); a1 += __shfl_xor(a1,4);
            a2 += __shfl_xor(a2,1); a2 += __shfl_xor(a2,2); a2 += __shfl_xor(a2,4);
            if (kl == 0) {
                bp[row]                   = (a0 + bb0) * SC_;
                bp[(size_t)NPAIR + row]   = (a1 + bb1) * SC_;
                bp[(size_t)2*NPAIR + row] = (a2 + bb2) * SC_;
            }
        }
    } else {
        // ---------------- proj_gemm ----------------
        constexpr int BM=64, BN=32, BK=32, LDA=68;
        float (*sA)[LDA] = (float(*)[LDA])smem;          // [32][68]
        float (*sB)[BN]  = (float(*)[BN])(smem + 2176);  // [32][32]
        const int bid = (int)blockIdx.x - ZWB_BLOCKS;
        const int m0 = (bid & 7) * BM;
        const int c0 = (bid >> 3) * BN;
        const int tx = t & 15, ty = t >> 4;

        float acc[4][2] = {};
        for (int kt = 0; kt < CS/BK; ++kt) {
            const int k0 = kt*BK;
            #pragma unroll
            for (int r = 0; r < 2; ++r) {
                int qd = r*256 + t;
                int m = qd >> 3, kq = (qd & 7) << 2;
                float4 f = *(const float4*)(s + (size_t)(m0+m)*CS + k0 + kq);
                sA[kq+0][m] = f.x; sA[kq+1][m] = f.y;
                sA[kq+2][m] = f.z; sA[kq+3][m] = f.w;
            }
            {
                int kk = t >> 3, c4 = (t & 7) << 2;
                int c = c0 + c4;
                const float* wp; int ld, co;
                if (c < 192)      { wp = wq;   ld = 192; co = c;     }
                else if (c < 576) { wp = wkv;  ld = 384; co = c-192; }
                else if (c < 720) { wp = wqp;  ld = 144; co = c-576; }
                else              { wp = wkvp; ld = 432; co = c-720; }
                float4 f = *(const float4*)(wp + (size_t)(k0+kk)*ld + co);
                *(float4*)&sB[kk][c4] = f;
            }
            __syncthreads();
            #pragma unroll
            for (int kk = 0; kk < BK; ++kk) {
                float4 a = *(const float4*)&sA[kk][ty*4];
                float2 b = *(const float2*)&sB[kk][tx*2];
                acc[0][0] += a.x*b.x; acc[0][1] += a.x*b.y;
                acc[1][0] += a.y*b.x; acc[1][1] += a.y*b.y;
                acc[2][0] += a.z*b.x; acc[2][1] += a.z*b.y;
                acc[3][0] += a.w*b.x; acc[3][1] += a.w*b.y;
            }
            __syncthreads();
        }
        float* qw  = ws + OFF_Q;  float* ktw = ws + OFF_KT;  float* vt = ws + OFF_VT;
        float* raw = ws + OFF_RAW;
        #pragma unroll
        for (int i = 0; i < 4; ++i)
            #pragma unroll
            for (int j = 0; j < 2; ++j) {
                int n = m0 + ty*4 + i;
                int c = c0 + tx*2 + j;
                if (c < 192) {
                    int hh = c >> 4, cc = c & 15;
                    qw[((size_t)hh*NRIG + n)*16 + cc] = acc[i][j] + bq[c];
                } else if (c < 576) {
                    int e = c-192; float val = acc[i][j] + bkv[e];
                    int hh = e >> 5, sub = e & 31;
                    if (sub < CH) ktw[((size_t)hh*16 + sub)*NRIG + n] = val;
                    else          vt [((size_t)hh*40 + (sub-CH))*NRIG + n] = val;
                } else {
                    int e = c-576;
                    float bb_ = (c < 720) ? bqp[e] : bkvp[c-720];
                    raw[(size_t)n*576 + e] = acc[i][j] + bb_;
                }
            }
    }
}

// =====================================================================
// Kernel 2: rotate raw local points -> global frame
// =====================================================================
__global__ __launch_bounds__(256) void rotate_kernel(
    const float* __restrict__ rot, const float* __restrict__ trans,
    const float* __restrict__ raw_in, float* __restrict__ qpw,
    float* __restrict__ kptw, float* __restrict__ vtw)
{
    const int gid = blockIdx.x*256 + threadIdx.x;
    const int n = gid / 192, d = gid % 192;
    const float* raw = raw_in + (size_t)n*576;
    float px, py, pzz;
    if (d < 48) { px = raw[d];      py = raw[48+d];       pzz = raw[96+d]; }
    else { int dd = d-48; px = raw[144+dd]; py = raw[288+dd]; pzz = raw[432+dd]; }
    const float* R = rot   + (size_t)n*9;
    const float* T = trans + (size_t)n*3;
    float gx = R[0]*px + R[1]*py + R[2]*pzz + T[0];
    float gy = R[3]*px + R[4]*py + R[5]*pzz + T[1];
    float gz = R[6]*px + R[7]*py + R[8]*pzz + T[2];
    if (d < 48) {                              // q_pts: d = h*4+p
        int hh = d >> 2, pp = d & 3;
        float* dst = qpw + ((size_t)hh*NRIG + n)*12 + pp*3;
        dst[0]=gx; dst[1]=gy; dst[2]=gz;
    } else {
        int dd = d-48; int hh = dd/12, pp = dd%12;
        if (pp < PQ) {
            float* kpt = kptw + (size_t)hh*12*NRIG;
            kpt[(size_t)(pp*3+0)*NRIG + n] = gx;
            kpt[(size_t)(pp*3+1)*NRIG + n] = gy;
            kpt[(size_t)(pp*3+2)*NRIG + n] = gz;
        } else {
            float* vt = vtw + ((size_t)hh*40 + 16 + (pp-PQ)*3)*NRIG + n;
            vt[0*NRIG]=gx; vt[1*NRIG]=gy; vt[2*NRIG]=gz;
        }
    }
}

// =====================================================================
// Kernel 3: attention. block = (h, 8 queries), 256 threads.
// =====================================================================
__global__ __launch_bounds__(256) void attn_kernel(
    const float* __restrict__ hw_in, const float* __restrict__ mask,
    const int* __restrict__ ridx,
    const float* __restrict__ qw_all,  const float* __restrict__ ktw_all,
    const float* __restrict__ qpw_all, const float* __restrict__ kpt_all,
    const float* __restrict__ vt_all,  const float* __restrict__ bp_all,
    float* __restrict__ o_out, float* __restrict__ opt_out, float* __restrict__ rs_out)
{
    constexpr int TI = 8;
    const int h    = blockIdx.x;
    const int i0   = blockIdx.y * TI;
    const int t    = threadIdx.x;
    const int lane = t & 63, wid = t >> 6;

    __shared__ float sE[TI*516];        // [qq][516], b32 conflict-free
    __shared__ float sP[16][TI][45];    // partial sums [g][qq][comp]
    __shared__ float sS[TI];

    const float* qw  = qw_all  + (size_t)h*NRIG*16;
    const float* ktw = ktw_all + (size_t)h*16*NRIG;
    const float* qpw = qpw_all + (size_t)h*NRIG*12;
    const float* kpt = kpt_all + (size_t)h*12*NRIG;
    const float* vt  = vt_all  + (size_t)h*40*NRIG;
    const float* bph = bp_all  + (size_t)h*NPAIR;

    const float hwv = -0.5f * log1pf(__expf(hw_in[h])) * 0.13608276348795434f; // -0.5*softplus*sqrt(1/54)
    const float QKS = 0.14433756729740643f;                                    // sqrt(1/48)

    // ---------- phase 1: logits -> exp -> sE ----------
    #pragma unroll
    for (int jj = 0; jj < 2; ++jj) {
        const int j = t + jj*256;
        float kk[16], kpv[12];
        #pragma unroll
        for (int c = 0; c < 16; ++c) kk[c]  = ktw[c*NRIG + j];   // coalesced
        #pragma unroll
        for (int e = 0; e < 12; ++e) kpv[e] = kpt[e*NRIG + j];   // coalesced
        const float mj = mask[j];
        const int   rj = ridx[j];
        #pragma unroll
        for (int qq = 0; qq < TI; ++qq) {
            const float* qv  = qw  + (size_t)(i0+qq)*16;   // uniform -> s_load
            const float* qpv = qpw + (size_t)(i0+qq)*12;   // uniform -> s_load
            const float  mi  = mask[i0+qq];                // uniform
            const int    ri  = ridx[i0+qq];                // uniform
            float dot = 0.f;
            #pragma unroll
            for (int c = 0; c < 16; ++c) dot += qv[c]*kk[c];
            float sq = 0.f;
            #pragma unroll
            for (int e = 0; e < 12; ++e) { float d = qpv[e]-kpv[e]; sq += d*d; }
            const float bv = bph[(size_t)ri*NRES + rj];    // L1-hot 1.8KB row
            const float lgt = dot*QKS + bv + hwv*sq + INF_*(mi*mj - 1.0f);
            sE[qq*516 + j] = __expf(lgt);
        }
    }
    __syncthreads();

    // ---------- phase 2: output GEMM. wave wid owns comps c = wid + 4*ci ----------
    {
        float acc[11][TI];
        #pragma unroll
        for (int ci=0;ci<11;++ci)
            #pragma unroll
            for (int qq=0;qq<TI;++qq) acc[ci][qq]=0.f;

        #pragma unroll
        for (int m = 0; m < 8; ++m) {
            const int j = lane + (m<<6);
            float ev[TI];
            #pragma unroll
            for (int qq=0;qq<TI;++qq) ev[qq] = sE[qq*516 + j];
            #pragma unroll
            for (int ci = 0; ci < 11; ++ci) {
                if (ci < 10 || wid == 0) {
                    const int c = wid + (ci<<2);                       // 0..40
                    const float vv = (c == 40) ? 1.0f : vt[(size_t)c*NRIG + j];
                    #pragma unroll
                    for (int qq=0;qq<TI;++qq) acc[ci][qq] += ev[qq]*vv;
                }
            }
        }
        #pragma unroll
        for (int ci=0;ci<11;++ci)
            if (ci < 10 || wid == 0)
                #pragma unroll
                for (int qq=0;qq<TI;++qq) {
                    acc[ci][qq] += __shfl_xor(acc[ci][qq], 1);
                    acc[ci][qq] += __shfl_xor(acc[ci][qq], 2);
                }
        if ((lane & 3) == 0) {
            const int g = lane >> 2;
            #pragma unroll
            for (int ci=0;ci<11;++ci)
                if (ci < 10 || wid == 0) {
                    const int c = wid + (ci<<2);
                    #pragma unroll
                    for (int qq=0;qq<TI;++qq) sP[g][qq][c] = acc[ci][qq];
                }
        }
    }
    __syncthreads();

    if (t < TI) {
        float S = 0.f;
        #pragma unroll
        for (int g = 0; g < 16; ++g) S += sP[g][t][40];
        sS[t] = S;
    }
    __syncthreads();

    // ---------- epilogue: 8*41 outputs ----------
    for (int e = t; e < TI*41; e += 256) {
        const int qq = e / 41, c = e % 41;
        const int n = i0 + qq;
        float sum = 0.f;
        #pragma unroll
        for (int g = 0; g < 16; ++g) sum += sP[g][qq][c];
        const float val = sum * (1.0f / sS[qq]);
        if (c < 16)       o_out[((size_t)n*NH + h)*CH + c]        = val;
        else if (c < 40)  opt_out[((size_t)n*NH + h)*24 + (c-16)] = val;
        else              rs_out[(size_t)n*NH + h]                = val;
    }
}

// =====================================================================
// Kernel 4: build feats F[512][960]; pz_diag computed in-block.
// =====================================================================
__global__ __launch_bounds__(256) void feats_kernel(
    const float* __restrict__ rot, const float* __restrict__ trans,
    const float* __restrict__ z, const int* __restrict__ ridx,
    const float* __restrict__ wdz, const float* __restrict__ bdz,
    const float* __restrict__ o_ws, const float* __restrict__ optg,
    const float* __restrict__ rs, float* __restrict__ F)
{
    constexpr int TI = 4;
    __shared__ float sZd[TI][CZ];
    __shared__ float sPz[TI][32];
    const int i0 = blockIdx.x*TI;
    const int t  = threadIdx.x;

    for (int e = t; e < TI*CZ; e += 256) {
        int qq = e >> 7, c = e & 127;
        int ri = ridx[i0+qq];
        sZd[qq][c] = z[((size_t)ri*NRES + ri)*CZ + c];
    }
    for (int e = t; e < TI*HC; e += 256) {
        int qq = e/HC, c = e%HC;
        F[(size_t)(i0+qq)*960 + c] = o_ws[(size_t)(i0+qq)*HC + c];
    }
    for (int e = t; e < TI*96; e += 256) {
        int qq = e/96, hp = e%96; int n = i0+qq;
        const float* g = optg + ((size_t)n*NH + hp/PV)*24 + (hp%PV)*3;
        float gx = g[0]-trans[n*3+0], gy = g[1]-trans[n*3+1], gz = g[2]-trans[n*3+2];
        const float* R = rot + (size_t)n*9;
        float lx = R[0]*gx + R[3]*gy + R[6]*gz;   // rot^T
        float ly = R[1]*gx + R[4]*gy + R[7]*gz;
        float lz = R[2]*gx + R[5]*gy + R[8]*gz;
        float* Fr = F + (size_t)n*960;
        Fr[192+hp] = lx; Fr[288+hp] = ly; Fr[384+hp] = lz;
        Fr[480+hp] = sqrtf(lx*lx+ly*ly+lz*lz + 1e-8f);
    }
    __syncthreads();
    if (t < TI*32) {
        int qq = t >> 5, d = t & 31;
        float acc = 0.f;
        #pragma unroll 8
        for (int c = 0; c < CZ; ++c) acc += sZd[qq][c] * wdz[(size_t)c*32 + d];
        sPz[qq][d] = acc + bdz[d];
    }
    __syncthreads();
    for (int e = t; e < TI*384; e += 256) {
        int qq = e/384, hd = e%384; int n = i0+qq;
        F[(size_t)n*960 + 576 + hd] = rs[(size_t)n*NH + (hd>>5)] * sPz[qq][hd&31];
    }
}

// =====================================================================
// Kernel 5: split-K GEMM  P[ks][512][384] = F[:, ks*320..+320] @ w_out-slice
// =====================================================================
__global__ __launch_bounds__(256) void out_gemm_kernel(
    const float* __restrict__ w_out, const float* __restrict__ F,
    float* __restrict__ P)
{
    constexpr int BM=64, BN=32, BK=32, LDA=68;
    __shared__ float sA[BK][LDA];
    __shared__ float sB[BK][BN];
    const int m0 = blockIdx.x * BM;
    const int c0 = blockIdx.y * BN;
    const int ks = blockIdx.z;
    const int t  = threadIdx.x;
    const int tx = t & 15, ty = t >> 4;

    float acc[4][2] = {};
    for (int kt = 0; kt < 10; ++kt) {
        const int k0 = ks*320 + kt*BK;
        #pragma unroll
        for (int r = 0; r < 2; ++r) {
            int qd = r*256 + t;
            int m = qd >> 3, kq = (qd & 7) << 2;
            float4 f = *(const float4*)(F + (size_t)(m0+m)*960 + k0 + kq);
            sA[kq+0][m] = f.x; sA[kq+1][m] = f.y;
            sA[kq+2][m] = f.z; sA[kq+3][m] = f.w;
        }
        {
            int kk = t >> 3, c4 = (t & 7) << 2;
            float4 f = *(const float4*)(w_out + (size_t)(k0+kk)*CS + c0 + c4);
            *(float4*)&sB[kk][c4] = f;
        }
        __syncthreads();
        #pragma unroll
        for (int kk = 0; kk < BK; ++kk) {
            float4 a = *(const float4*)&sA[kk][ty*4];
            float2 b = *(const float2*)&sB[kk][tx*2];
            acc[0][0] += a.x*b.x; acc[0][1] += a.x*b.y;
            acc[1][0] += a.y*b.x; acc[1][1] += a.y*b.y;
            acc[2][0] += a.z*b.x; acc[2][1] += a.z*b.y;
            acc[3][0] += a.w*b.x; acc[3][1] += a.w*b.y;
        }
        __syncthreads();
    }
    #pragma unroll
    for (int i = 0; i < 4; ++i)
        #pragma unroll
        for (int j = 0; j < 2; ++j) {
            int n = m0 + ty*4 + i;
            int c = c0 + tx*2 + j;
            P[(size_t)ks*NRIG*CS + (size_t)n*CS + c] = acc[i][j];
        }
}

// =====================================================================
// Kernel 6: reduce split-K partials + bias
// =====================================================================
__global__ __launch_bounds__(256) void reduce_kernel(
    const float* __restrict__ P, const float* __restrict__ b_out,
    float* __restrict__ out)
{
    const int i4 = blockIdx.x*256 + threadIdx.x;
    const size_t base = (size_t)i4 * 4;
    float4 a = *(const float4*)(P + base);
    float4 b = *(const float4*)(P + (size_t)NRIG*CS + base);
    float4 c = *(const float4*)(P + (size_t)2*NRIG*CS + base);
    const int cc = (int)(base % CS);
    float4 bv = *(const float4*)(b_out + cc);
    float4 r;
    r.x = a.x+b.x+c.x+bv.x; r.y = a.y+b.y+c.y+bv.y;
    r.z = a.z+b.z+c.z+bv.z; r.w = a.w+b.w+c.w+bv.w;
    *(float4*)(out + base) = r;
}

// =====================================================================
extern "C" void kernel_launch(void* const* d_in, const int* in_sizes, int n_in,
                              void* d_out, int out_size, void* d_ws, size_t ws_size,
                              hipStream_t stream)
{
    const float* s     = (const float*)d_in[0];
    const float* z     = (const float*)d_in[1];
    const float* rot   = (const float*)d_in[2];
    const float* trans = (const float*)d_in[3];
    const float* mask  = (const float*)d_in[4];
    const int*   ridx  = (const int*)  d_in[5];
    const float* wq    = (const float*)d_in[6];
    const float* bq    = (const float*)d_in[7];
    const float* wkv   = (const float*)d_in[8];
    const float* bkv   = (const float*)d_in[9];
    const float* wqp   = (const float*)d_in[10];
    const float* bqp   = (const float*)d_in[11];
    const float* wkvp  = (const float*)d_in[12];
    const float* bkvp  = (const float*)d_in[13];
    const float* wb    = (const float*)d_in[14];
    const float* bb    = (const float*)d_in[15];
    const float* wdz   = (const float*)d_in[16];
    const float* bdz   = (const float*)d_in[17];
    const float* hw    = (const float*)d_in[18];
    const float* wout  = (const float*)d_in[19];
    const float* bout  = (const float*)d_in[20];
    float* ws  = (float*)d_ws;
    float* out = (float*)d_out;

    hipLaunchKernelGGL(prep_kernel, dim3(ZWB_BLOCKS + 288), dim3(256), 0, stream,
        z, wb, bb, s, wq,bq, wkv,bkv, wqp,bqp, wkvp,bkvp, ws);
    hipLaunchKernelGGL(rotate_kernel, dim3(NRIG*192/256), dim3(256), 0, stream,
        rot, trans, ws+OFF_RAW, ws+OFF_QP, ws+OFF_KPT, ws+OFF_VT);
    hipLaunchKernelGGL(attn_kernel, dim3(NH, NRIG/8), dim3(256), 0, stream,
        hw, mask, ridx, ws+OFF_Q, ws+OFF_KT, ws+OFF_QP, ws+OFF_KPT,
        ws+OFF_VT, ws+OFF_BP, ws+OFF_O, ws+OFF_OPT, ws+OFF_RS);
    hipLaunchKernelGGL(feats_kernel, dim3(NRIG/4), dim3(256), 0, stream,
        rot, trans, z, ridx, wdz, bdz, ws+OFF_O, ws+OFF_OPT, ws+OFF_RS, ws+OFF_F);
    hipLaunchKernelGGL(out_gemm_kernel, dim3(NRIG/64, CS/32, 3), dim3(256), 0, stream,
        wout, ws+OFF_F, ws+OFF_P3);
    hipLaunchKernelGGL(reduce_kernel, dim3(NRIG*CS/4/256), dim3(256), 0, stream,
        ws+OFF_P3, bout, out);
}